// Round 16
// baseline (189.749 us; speedup 1.0000x reference)
//
#include <hip/hip_runtime.h>

// ---------- helpers ----------
static __device__ __forceinline__ void fma4(float4& a, float s, float4 v) {
  a.x = fmaf(s, v.x, a.x);
  a.y = fmaf(s, v.y, a.y);
  a.z = fmaf(s, v.z, a.z);
  a.w = fmaf(s, v.w, a.w);
}
static __device__ __forceinline__ float4 relu4(float4 a) {
  return make_float4(fmaxf(a.x, 0.f), fmaxf(a.y, 0.f),
                     fmaxf(a.z, 0.f), fmaxf(a.w, 0.f));
}
typedef float floatv4 __attribute__((ext_vector_type(4)));
static __device__ __forceinline__ float4 ntld4(const float* p) {
  floatv4 v = __builtin_nontemporal_load(reinterpret_cast<const floatv4*>(p));
  return make_float4(v.x, v.y, v.z, v.w);
}

// ---------- transpose x (16,C,H,W) -> xt [C][H][W][16] ----------
__global__ void k_transpose(const float* __restrict__ x, float* __restrict__ xt,
                            int chw, int total) {
  int p = blockIdx.x * blockDim.x + threadIdx.x;
  if (p >= total) return;
  float v[16];
#pragma unroll
  for (int b = 0; b < 16; ++b) v[b] = x[(size_t)b * chw + p];
  float4* o4 = reinterpret_cast<float4*>(xt) + (size_t)p * 4;
#pragma unroll
  for (int q = 0; q < 4; ++q)
    o4[q] = make_float4(v[4 * q + 0], v[4 * q + 1], v[4 * q + 2], v[4 * q + 3]);
}

// ---------- L1 LC: async global_load_lds staging + double-buffered LDS ------
// O_BLK=2 o-channels/block; LDS 2 bufs x 1152 float4 = 36,864B (4 blocks/CU).
// stage(c+1) is issued BEFORE compute(c), so the single __syncthreads per c
// (vmcnt(0) drain) finds staging complete: zero exposed staging latency.
// LDS dest is wave-uniform base + lane*16 (HW rule); global src is per-lane
// (clamped for edge tiles; garbage slots never read).
__global__ __launch_bounds__(256) void k_lc1_glds(
    const float* __restrict__ xt, const float* __restrict__ wgt,
    const float* __restrict__ bias, float* __restrict__ out) {
  constexpr int C = 3, IH = 218, IW = 178, OH = 213, OW = 173;
  constexpr int POS = OH * OW;        // 36849
  constexpr int NT = (POS + 63) / 64; // 576
  constexpr size_t W1F4MAX = (size_t)8 * C * POS * 9 - 1;
  __shared__ float4 wl[2][2 * 64 * 9];

  const int tile = blockIdx.x % NT;
  const int ob0 = (blockIdx.x / NT) * 2;
  const int p0 = tile * 64;
  const int PN = (POS - p0) < 64 ? (POS - p0) : 64;
  const int lp = threadIdx.x >> 2, bq = threadIdx.x & 3;
  const int wid = threadIdx.x >> 6, lane = threadIdx.x & 63;
  const int fp = p0 + lp;
  const bool act = lp < PN;
  const int h = act ? fp / OW : 0;
  const int w = act ? fp % OW : 0;

  const float4* x4 = reinterpret_cast<const float4*>(xt);
  const float4* w4 = reinterpret_cast<const float4*>(wgt);

  float4 acc[2];
#pragma unroll
  for (int o = 0; o < 2; ++o) {
    float bv = act ? bias[(size_t)(ob0 + o) * POS + fp] : 0.f;
    acc[o] = make_float4(bv, bv, bv, bv);
  }

  // ---- async stage issue: 18 chunks of 64 float4, wave-strided ----
  auto stage = [&](int buf, int c) {
    for (int j = wid; j < 18; j += 4) {
      int e = j * 64 + lane;
      int o_l = e / 576, rem = e % 576;
      size_t g = ((size_t)((ob0 + o_l) * C + c) * POS + p0) * 9 + rem;
      if (g > W1F4MAX) g = W1F4MAX;
      __builtin_amdgcn_global_load_lds(w4 + g, &wl[buf][j * 64], 16, 0, 0);
    }
  };

  stage(0, 0);
  for (int c = 0; c < C; ++c) {
    __syncthreads();  // drains vmcnt: wl[c&1] ready (issued one phase ago)
    if (c + 1 < C) stage((c + 1) & 1, c + 1);
    if (act) {
      const float4* xc = x4 + ((size_t)(c * IH + h) * IW + w) * 4 + bq;
#pragma unroll
      for (int k4 = 0; k4 < 9; ++k4) {
        float4 xv[4];
#pragma unroll
        for (int r = 0; r < 4; ++r) {
          int k = k4 * 4 + r;
          xv[r] = xc[((k / 6) * IW + (k % 6)) * 4];
        }
#pragma unroll
        for (int o = 0; o < 2; ++o) {
          float4 wv = wl[c & 1][(o * 64 + lp) * 9 + k4];
          fma4(acc[o], wv.x, xv[0]);
          fma4(acc[o], wv.y, xv[1]);
          fma4(acc[o], wv.z, xv[2]);
          fma4(acc[o], wv.w, xv[3]);
        }
      }
    }
  }
  if (act) {
#pragma unroll
    for (int o = 0; o < 2; ++o)
      reinterpret_cast<float4*>(out)[((size_t)(ob0 + o) * POS + fp) * 4 + bq] =
          relu4(acc[o]);
  }
}

// ---------- LDS-staged LC partial: one c per block (L2/L3) ------------------
template <int C, int IH, int IW, int OH, int OW, int S, int O_TOT>
__global__ __launch_bounds__(256) void k_lc_lds_part(
    const float* __restrict__ xt, const float* __restrict__ wgt,
    float* __restrict__ part) {
  constexpr int POS = OH * OW;
  constexpr int NT = (POS + 63) / 64;
  constexpr int OGN = O_TOT / 4;
  __shared__ float4 wl[4 * 64 * 9];
  int tile = blockIdx.x % NT;
  int rem = blockIdx.x / NT;
  int ob0 = (rem % OGN) * 4;
  int c = rem / OGN;
  int p0 = tile * 64;
  int PN = (POS - p0) < 64 ? (POS - p0) : 64;
  int lp = threadIdx.x >> 2, bq = threadIdx.x & 3;
  int fp = p0 + lp;
  bool act = lp < PN;
  int h = act ? fp / OW : 0;
  int w = act ? fp % OW : 0;

  const float4* x4 = reinterpret_cast<const float4*>(xt);
  const float4* w4 = reinterpret_cast<const float4*>(wgt);

  for (int i = threadIdx.x; i < 2304; i += 256) {
    int o_l = i / 576;
    int r = i % 576;
    int pos = r / 9;
    int k4 = r % 9;
    if (pos < PN)
      wl[(o_l * 64 + pos) * 9 + k4] =
          w4[((size_t)((ob0 + o_l) * C + c) * POS + p0 + pos) * 9 + k4];
  }
  __syncthreads();
  if (!act) return;

  float4 acc[4];
#pragma unroll
  for (int o = 0; o < 4; ++o) acc[o] = make_float4(0.f, 0.f, 0.f, 0.f);

  const float4* xc = x4 + ((size_t)(c * IH + h * S) * IW + w * S) * 4 + bq;
#pragma unroll
  for (int k4 = 0; k4 < 9; ++k4) {
    float4 xv[4];
#pragma unroll
    for (int r = 0; r < 4; ++r) {
      int k = k4 * 4 + r;
      xv[r] = xc[((k / 6) * IW + (k % 6)) * 4];
    }
#pragma unroll
    for (int o = 0; o < 4; ++o) {
      float4 wv = wl[(o * 64 + lp) * 9 + k4];
      fma4(acc[o], wv.x, xv[0]);
      fma4(acc[o], wv.y, xv[1]);
      fma4(acc[o], wv.z, xv[2]);
      fma4(acc[o], wv.w, xv[3]);
    }
  }
  float4* pp = reinterpret_cast<float4*>(part) + (size_t)c * (O_TOT * POS * 4);
#pragma unroll
  for (int o = 0; o < 4; ++o)
    pp[((size_t)(ob0 + o) * POS + fp) * 4 + bq] = acc[o];
}

// ---------- combine partials: sum CC chunks + bias + relu -------------------
template <int CC, bool A3T>
__global__ void k_combine(const float* __restrict__ part,
                          const float* __restrict__ bias,
                          float* __restrict__ out, int n4total) {
  int p = blockIdx.x * blockDim.x + threadIdx.x;
  if (p >= n4total) return;
  const float4* p4 = reinterpret_cast<const float4*>(part);
  float4 acc = make_float4(0.f, 0.f, 0.f, 0.f);
#pragma unroll
  for (int c = 0; c < CC; ++c) {
    float4 v = p4[(size_t)c * n4total + p];
    acc.x += v.x; acc.y += v.y; acc.z += v.z; acc.w += v.w;
  }
  float bv = bias[p >> 2];
  acc = relu4(make_float4(acc.x + bv, acc.y + bv, acc.z + bv, acc.w + bv));
  if (A3T) {
    int k = p >> 2;
    int bq = p & 3;
    out[(size_t)(bq * 4 + 0) * 6144 + k] = acc.x;
    out[(size_t)(bq * 4 + 1) * 6144 + k] = acc.y;
    out[(size_t)(bq * 4 + 2) * 6144 + k] = acc.z;
    out[(size_t)(bq * 4 + 3) * 6144 + k] = acc.w;
  } else {
    reinterpret_cast<float4*>(out)[p] = acc;
  }
}

// ---------- 2x2 maxpool on [O][IH][IW][16] -> [O][PH][PW][16] ----------
__global__ void k_pool(const float* __restrict__ in, float* __restrict__ out,
                       int IH, int IW, int PH, int PW, int total) {
  int t = blockIdx.x * blockDim.x + threadIdx.x;
  if (t >= total) return;
  int bq = t & 3;
  int p = t >> 2;
  int w = p % PW; p /= PW;
  int h = p % PH; p /= PH;
  int o = p;
  const float4* in4 = reinterpret_cast<const float4*>(in);
  size_t r0 = ((size_t)(o * IH + 2 * h) * IW + 2 * w) * 4 + bq;
  float4 a = in4[r0];
  float4 b = in4[r0 + 4];
  float4 c = in4[r0 + (size_t)IW * 4];
  float4 d = in4[r0 + (size_t)IW * 4 + 4];
  float4 m;
  m.x = fmaxf(fmaxf(a.x, b.x), fmaxf(c.x, d.x));
  m.y = fmaxf(fmaxf(a.y, b.y), fmaxf(c.y, d.y));
  m.z = fmaxf(fmaxf(a.z, b.z), fmaxf(c.z, d.z));
  m.w = fmaxf(fmaxf(a.w, b.w), fmaxf(c.w, d.w));
  reinterpret_cast<float4*>(out)[((size_t)(o * PH + h) * PW + w) * 4 + bq] = m;
}

// ---------- FC stage 1 (best-measured: KC=2, dbuf + non-temporal wf) --------
constexpr int FC_N = 10178;
constexpr int FC_K = 6144;
constexpr int FC_KC = 2;
constexpr int FC_KLEN = FC_K / FC_KC;  // 3072

__global__ __launch_bounds__(256) void k_fc(const float* __restrict__ a3t,
                                            const float* __restrict__ wf,
                                            float* __restrict__ fcp) {
  int wv = threadIdx.x >> 6;
  int l = threadIdx.x & 63;
  int n0 = (blockIdx.x * 4 + wv) * 4;
  int kc = blockIdx.y;
  int kbase = kc * FC_KLEN;

  float acc[64];
#pragma unroll
  for (int j = 0; j < 64; ++j) acc[j] = 0.f;

  int n[4];
#pragma unroll
  for (int m = 0; m < 4; ++m) {
    int nn = n0 + m;
    n[m] = nn < FC_N ? nn : FC_N - 1;
  }

  float4 wr[4];
  {
    int k = kbase + 4 * l;
#pragma unroll
    for (int m = 0; m < 4; ++m) wr[m] = ntld4(wf + (size_t)n[m] * FC_K + k);
  }

  for (int k0 = 0; k0 < FC_KLEN; k0 += 256) {
    int k = kbase + k0 + 4 * l;
    int kp = (k0 + 256 < FC_KLEN) ? (k + 256) : (kbase + 4 * l);
    float4 wrn[4];
#pragma unroll
    for (int m = 0; m < 4; ++m) wrn[m] = ntld4(wf + (size_t)n[m] * FC_K + kp);

#pragma unroll
    for (int bg = 0; bg < 4; ++bg) {
      float4 xv[4];
#pragma unroll
      for (int r = 0; r < 4; ++r)
        xv[r] = *reinterpret_cast<const float4*>(a3t +
                    (size_t)(bg * 4 + r) * FC_K + k);
#pragma unroll
      for (int r = 0; r < 4; ++r) {
        int b = bg * 4 + r;
#pragma unroll
        for (int m = 0; m < 4; ++m) {
          int j = b * 4 + m;
          acc[j] = fmaf(wr[m].x, xv[r].x, acc[j]);
          acc[j] = fmaf(wr[m].y, xv[r].y, acc[j]);
          acc[j] = fmaf(wr[m].z, xv[r].z, acc[j]);
          acc[j] = fmaf(wr[m].w, xv[r].w, acc[j]);
        }
      }
      __builtin_amdgcn_sched_barrier(0);
    }
#pragma unroll
    for (int m = 0; m < 4; ++m) wr[m] = wrn[m];
  }

#pragma unroll
  for (int s = 0; s < 6; ++s) {
    int mask = 1 << s;
    int bit = (l >> s) & 1;
#pragma unroll
    for (int t = 0; t < 32; ++t) {
      if (t < (64 >> (s + 1))) {
        float e = acc[2 * t] + __shfl_xor(acc[2 * t], mask, 64);
        float o = acc[2 * t + 1] + __shfl_xor(acc[2 * t + 1], mask, 64);
        acc[t] = bit ? o : e;
      }
    }
  }

  int b = l >> 2;
  int m = l & 3;
  int nn = n0 + m;
  if (nn < FC_N)
    fcp[((size_t)kc * 16 + b) * FC_N + nn] = acc[0];
}

// ---------- FC stage 2: sum k-chunks + bias ----------
__global__ void k_fc_comb(const float* __restrict__ fcp,
                          const float* __restrict__ bf,
                          float* __restrict__ out, int total) {
  int t = blockIdx.x * blockDim.x + threadIdx.x;
  if (t >= total) return;
  unsigned n = (unsigned)t % (unsigned)FC_N;
  float s = bf[n];
#pragma unroll
  for (int kc = 0; kc < FC_KC; ++kc) s += fcp[(size_t)kc * 16 * FC_N + t];
  out[t] = s;
}

// ---------- launch ----------
static inline int cdiv(int a, int b) { return (a + b - 1) / b; }

extern "C" void kernel_launch(void* const* d_in, const int* in_sizes, int n_in,
                              void* d_out, int out_size, void* d_ws,
                              size_t ws_size, hipStream_t stream) {
  const float* x  = (const float*)d_in[0];  // (16,3,218,178)
  const float* w1 = (const float*)d_in[1];  // (8,3,213,173,36)
  const float* b1 = (const float*)d_in[2];  // (8,213,173)
  const float* w2 = (const float*)d_in[3];  // (16,8,51,41,36)
  const float* b2 = (const float*)d_in[4];  // (16,51,41)
  const float* w3 = (const float*)d_in[5];  // (32,16,16,12,36)
  const float* b3 = (const float*)d_in[6];  // (32,16,12)
  const float* wf = (const float*)d_in[7];  // (10178,6144)
  const float* bf = (const float*)d_in[8];  // (10178,)
  float* out = (float*)d_out;               // (16,10178)

  float* ws = (float*)d_ws;
  float* xt     = ws;                  // 1,862,592 floats (free after L1)
  float* a1     = ws + 1862592;        // 4,716,672 (free after pool)
  float* a1p    = ws + 6579264;        // 1,166,848 (free after L2 partials)
  float* a2     = ws + 7746112;        //   535,296
  float* a3t    = ws + 8281408;        //    98,304
  float* l2part = a1;                  // 8 * 535,296 = 4,282,368 <= a1
  float* l3part = xt;                  // 16 * 98,304 = 1,572,864 <= xt
  float* fcp    = a1p;                 // 2 * 162,848 =   325,696 <= a1p

  {  // transpose x -> xt
    int total = 3 * 218 * 178;
    k_transpose<<<cdiv(total, 256), 256, 0, stream>>>(x, xt, total, total);
  }
  {  // L1: async-staged dbuf, O_BLK=2 -> 576 tiles x 4 o-groups = 2304 blocks
    k_lc1_glds<<<576 * 4, 256, 0, stream>>>(xt, w1, b1, a1);
  }
  {  // maxpool2 -> 106x86
    int total = 4 * 8 * 106 * 86;
    k_pool<<<cdiv(total, 256), 256, 0, stream>>>(a1, a1p, 213, 173, 106, 86,
                                                 total);
  }
  {  // L2 partials: POS=2091, NT=33, OGN=4, C=8 -> 1056 blocks
    k_lc_lds_part<8, 106, 86, 51, 41, 2, 16>
        <<<33 * 4 * 8, 256, 0, stream>>>(a1p, w2, l2part);
  }
  {  // L2 combine -> a2
    int n4 = 16 * 2091 * 4;
    k_combine<8, false><<<cdiv(n4, 256), 256, 0, stream>>>(l2part, b2, a2, n4);
  }
  {  // L3 partials: POS=192, NT=3, OGN=8, C=16 -> 384 blocks
    k_lc_lds_part<16, 51, 41, 16, 12, 3, 32>
        <<<3 * 8 * 16, 256, 0, stream>>>(a2, w3, l3part);
  }
  {  // L3 combine -> a3t [16][6144]
    int n4 = 32 * 192 * 4;
    k_combine<16, true><<<cdiv(n4, 256), 256, 0, stream>>>(l3part, b3, a3t, n4);
  }
  {  // FC stage 1: (637, 2) -> 5096 waves
    dim3 grid(cdiv(FC_N, 16), FC_KC);
    k_fc<<<grid, 256, 0, stream>>>(a3t, wf, fcp);
  }
  {  // FC stage 2
    int total = 16 * FC_N;
    k_fc_comb<<<cdiv(total, 256), 256, 0, stream>>>(fcp, bf, out, total);
  }
}

// Round 17
// 174.258 us; speedup vs baseline: 1.0889x; 1.0889x over previous
//
#include <hip/hip_runtime.h>
#include <hip/hip_fp16.h>

// ---------- helpers ----------
static __device__ __forceinline__ void fma4(float4& a, float s, float4 v) {
  a.x = fmaf(s, v.x, a.x);
  a.y = fmaf(s, v.y, a.y);
  a.z = fmaf(s, v.z, a.z);
  a.w = fmaf(s, v.w, a.w);
}
static __device__ __forceinline__ float4 relu4(float4 a) {
  return make_float4(fmaxf(a.x, 0.f), fmaxf(a.y, 0.f),
                     fmaxf(a.z, 0.f), fmaxf(a.w, 0.f));
}
typedef float floatv4 __attribute__((ext_vector_type(4)));
static __device__ __forceinline__ float4 ntld4(const float* p) {
  floatv4 v = __builtin_nontemporal_load(reinterpret_cast<const floatv4*>(p));
  return make_float4(v.x, v.y, v.z, v.w);
}
static __device__ __forceinline__ unsigned h2u(__half2 h) {
  union { __half2 h; unsigned u; } c;
  c.h = h;
  return c.u;
}
static __device__ __forceinline__ __half2 u2h(unsigned u) {
  union { unsigned u; __half2 h; } c;
  c.u = u;
  return c.h;
}

// ---------- transpose x (16,C,H,W) -> xh [C][H][W][16] fp16 ----------
// pos-major; batch pair (2q,2q+1) packed in one __half2 (low = even batch).
__global__ void k_transpose_h(const float* __restrict__ x,
                              unsigned* __restrict__ xh, int chw, int total) {
  int p = blockIdx.x * blockDim.x + threadIdx.x;
  if (p >= total) return;
  unsigned d[8];
#pragma unroll
  for (int q = 0; q < 8; ++q)
    d[q] = h2u(__floats2half2_rn(x[(size_t)(2 * q) * chw + p],
                                 x[(size_t)(2 * q + 1) * chw + p]));
  uint4* o4 = reinterpret_cast<uint4*>(xh + (size_t)p * 8);
  o4[0] = make_uint4(d[0], d[1], d[2], d[3]);
  o4[1] = make_uint4(d[4], d[5], d[6], d[7]);
}

// ---------- L1 LC via packed-fp16 FMA (v_pk_fma_f16), R6 structure ---------
// block = 256 (64 pos x 4 bq); thread covers 4 batches = 2 half2 accs per o.
// LDS: wl dup-pairs [4o][64pos][36taps] x 4B = 36,864 B (4 blocks/CU).
// Output a1 stays fp32 [o][pos][16].
__global__ __launch_bounds__(256) void k_lc1_h2(
    const unsigned* __restrict__ xh, const float* __restrict__ wgt,
    const float* __restrict__ bias, float* __restrict__ out) {
  constexpr int C = 3, IH = 218, IW = 178, OH = 213, OW = 173;
  constexpr int POS = OH * OW;  // 36849
  constexpr int NT = (POS + 63) / 64;  // 576
  __shared__ unsigned wl[4 * 64 * 36];  // dup half2 per tap

  int tile = blockIdx.x % NT;
  int ob0 = (blockIdx.x / NT) * 4;
  int p0 = tile * 64;
  int PN = (POS - p0) < 64 ? (POS - p0) : 64;
  int lp = threadIdx.x >> 2, bq = threadIdx.x & 3;
  int fp = p0 + lp;
  bool act = lp < PN;
  int h = act ? fp / OW : 0;
  int w = act ? fp % OW : 0;

  __half2 acc[4][2];
#pragma unroll
  for (int o = 0; o < 4; ++o) {
    float bv = act ? bias[(size_t)(ob0 + o) * POS + fp] : 0.f;
    acc[o][0] = acc[o][1] = __float2half2_rn(bv);
  }

  const float4* w4 = reinterpret_cast<const float4*>(wgt);

  for (int c = 0; c < C; ++c) {
    __syncthreads();
    // stage weights: per unit i -> (o_l, pos, k4 of 4 taps); dup-pair convert
    for (int i = threadIdx.x; i < 2304; i += 256) {
      int o_l = i / 576;
      int r = i % 576;
      int pos = r / 9;
      int k4 = r % 9;
      if (pos < PN) {
        float4 v =
            w4[((size_t)((ob0 + o_l) * C + c) * POS + p0 + pos) * 9 + k4];
        uint4 u;
        u.x = h2u(__float2half2_rn(v.x));
        u.y = h2u(__float2half2_rn(v.y));
        u.z = h2u(__float2half2_rn(v.z));
        u.w = h2u(__float2half2_rn(v.w));
        *reinterpret_cast<uint4*>(&wl[(o_l * 64 + pos) * 36 + k4 * 4]) = u;
      }
    }
    __syncthreads();
    if (act) {
      // x base for this (c, h, w): unsigned units of 8 per position
      const unsigned* xc =
          xh + ((size_t)(c * IH + h) * IW + w) * 8 + 2 * bq;
#pragma unroll
      for (int k4 = 0; k4 < 9; ++k4) {
        uint2 xu[4];
#pragma unroll
        for (int r = 0; r < 4; ++r) {
          int k = k4 * 4 + r;
          xu[r] = *reinterpret_cast<const uint2*>(
              xc + ((k / 6) * IW + (k % 6)) * 8);
        }
#pragma unroll
        for (int o = 0; o < 4; ++o) {
          const unsigned* wp = &wl[(o * 64 + lp) * 36 + k4 * 4];
#pragma unroll
          for (int r = 0; r < 4; ++r) {
            __half2 wv = u2h(wp[r]);
            acc[o][0] = __hfma2(wv, u2h(xu[r].x), acc[o][0]);
            acc[o][1] = __hfma2(wv, u2h(xu[r].y), acc[o][1]);
          }
        }
      }
    }
  }
  if (act) {
#pragma unroll
    for (int o = 0; o < 4; ++o) {
      float4 r;
      r.x = fmaxf(__low2float(acc[o][0]), 0.f);
      r.y = fmaxf(__high2float(acc[o][0]), 0.f);
      r.z = fmaxf(__low2float(acc[o][1]), 0.f);
      r.w = fmaxf(__high2float(acc[o][1]), 0.f);
      reinterpret_cast<float4*>(out)[((size_t)(ob0 + o) * POS + fp) * 4 + bq] =
          r;
    }
  }
}

// ---------- LDS-staged LC partial: one c per block (L2/L3) ------------------
template <int C, int IH, int IW, int OH, int OW, int S, int O_TOT>
__global__ __launch_bounds__(256) void k_lc_lds_part(
    const float* __restrict__ xt, const float* __restrict__ wgt,
    float* __restrict__ part) {
  constexpr int POS = OH * OW;
  constexpr int NT = (POS + 63) / 64;
  constexpr int OGN = O_TOT / 4;
  __shared__ float4 wl[4 * 64 * 9];
  int tile = blockIdx.x % NT;
  int rem = blockIdx.x / NT;
  int ob0 = (rem % OGN) * 4;
  int c = rem / OGN;
  int p0 = tile * 64;
  int PN = (POS - p0) < 64 ? (POS - p0) : 64;
  int lp = threadIdx.x >> 2, bq = threadIdx.x & 3;
  int fp = p0 + lp;
  bool act = lp < PN;
  int h = act ? fp / OW : 0;
  int w = act ? fp % OW : 0;

  const float4* x4 = reinterpret_cast<const float4*>(xt);
  const float4* w4 = reinterpret_cast<const float4*>(wgt);

  for (int i = threadIdx.x; i < 2304; i += 256) {
    int o_l = i / 576;
    int r = i % 576;
    int pos = r / 9;
    int k4 = r % 9;
    if (pos < PN)
      wl[(o_l * 64 + pos) * 9 + k4] =
          w4[((size_t)((ob0 + o_l) * C + c) * POS + p0 + pos) * 9 + k4];
  }
  __syncthreads();
  if (!act) return;

  float4 acc[4];
#pragma unroll
  for (int o = 0; o < 4; ++o) acc[o] = make_float4(0.f, 0.f, 0.f, 0.f);

  const float4* xc = x4 + ((size_t)(c * IH + h * S) * IW + w * S) * 4 + bq;
#pragma unroll
  for (int k4 = 0; k4 < 9; ++k4) {
    float4 xv[4];
#pragma unroll
    for (int r = 0; r < 4; ++r) {
      int k = k4 * 4 + r;
      xv[r] = xc[((k / 6) * IW + (k % 6)) * 4];
    }
#pragma unroll
    for (int o = 0; o < 4; ++o) {
      float4 wv = wl[(o * 64 + lp) * 9 + k4];
      fma4(acc[o], wv.x, xv[0]);
      fma4(acc[o], wv.y, xv[1]);
      fma4(acc[o], wv.z, xv[2]);
      fma4(acc[o], wv.w, xv[3]);
    }
  }
  float4* pp = reinterpret_cast<float4*>(part) + (size_t)c * (O_TOT * POS * 4);
#pragma unroll
  for (int o = 0; o < 4; ++o)
    pp[((size_t)(ob0 + o) * POS + fp) * 4 + bq] = acc[o];
}

// ---------- combine partials: sum CC chunks + bias + relu -------------------
template <int CC, bool A3T>
__global__ void k_combine(const float* __restrict__ part,
                          const float* __restrict__ bias,
                          float* __restrict__ out, int n4total) {
  int p = blockIdx.x * blockDim.x + threadIdx.x;
  if (p >= n4total) return;
  const float4* p4 = reinterpret_cast<const float4*>(part);
  float4 acc = make_float4(0.f, 0.f, 0.f, 0.f);
#pragma unroll
  for (int c = 0; c < CC; ++c) {
    float4 v = p4[(size_t)c * n4total + p];
    acc.x += v.x; acc.y += v.y; acc.z += v.z; acc.w += v.w;
  }
  float bv = bias[p >> 2];
  acc = relu4(make_float4(acc.x + bv, acc.y + bv, acc.z + bv, acc.w + bv));
  if (A3T) {
    int k = p >> 2;
    int bq = p & 3;
    out[(size_t)(bq * 4 + 0) * 6144 + k] = acc.x;
    out[(size_t)(bq * 4 + 1) * 6144 + k] = acc.y;
    out[(size_t)(bq * 4 + 2) * 6144 + k] = acc.z;
    out[(size_t)(bq * 4 + 3) * 6144 + k] = acc.w;
  } else {
    reinterpret_cast<float4*>(out)[p] = acc;
  }
}

// ---------- 2x2 maxpool on [O][IH][IW][16] -> [O][PH][PW][16] ----------
__global__ void k_pool(const float* __restrict__ in, float* __restrict__ out,
                       int IH, int IW, int PH, int PW, int total) {
  int t = blockIdx.x * blockDim.x + threadIdx.x;
  if (t >= total) return;
  int bq = t & 3;
  int p = t >> 2;
  int w = p % PW; p /= PW;
  int h = p % PH; p /= PH;
  int o = p;
  const float4* in4 = reinterpret_cast<const float4*>(in);
  size_t r0 = ((size_t)(o * IH + 2 * h) * IW + 2 * w) * 4 + bq;
  float4 a = in4[r0];
  float4 b = in4[r0 + 4];
  float4 c = in4[r0 + (size_t)IW * 4];
  float4 d = in4[r0 + (size_t)IW * 4 + 4];
  float4 m;
  m.x = fmaxf(fmaxf(a.x, b.x), fmaxf(c.x, d.x));
  m.y = fmaxf(fmaxf(a.y, b.y), fmaxf(c.y, d.y));
  m.z = fmaxf(fmaxf(a.z, b.z), fmaxf(c.z, d.z));
  m.w = fmaxf(fmaxf(a.w, b.w), fmaxf(c.w, d.w));
  reinterpret_cast<float4*>(out)[((size_t)(o * PH + h) * PW + w) * 4 + bq] = m;
}

// ---------- FC stage 1 (best-measured: KC=2, dbuf + non-temporal wf) --------
constexpr int FC_N = 10178;
constexpr int FC_K = 6144;
constexpr int FC_KC = 2;
constexpr int FC_KLEN = FC_K / FC_KC;  // 3072

__global__ __launch_bounds__(256) void k_fc(const float* __restrict__ a3t,
                                            const float* __restrict__ wf,
                                            float* __restrict__ fcp) {
  int wv = threadIdx.x >> 6;
  int l = threadIdx.x & 63;
  int n0 = (blockIdx.x * 4 + wv) * 4;
  int kc = blockIdx.y;
  int kbase = kc * FC_KLEN;

  float acc[64];
#pragma unroll
  for (int j = 0; j < 64; ++j) acc[j] = 0.f;

  int n[4];
#pragma unroll
  for (int m = 0; m < 4; ++m) {
    int nn = n0 + m;
    n[m] = nn < FC_N ? nn : FC_N - 1;
  }

  float4 wr[4];
  {
    int k = kbase + 4 * l;
#pragma unroll
    for (int m = 0; m < 4; ++m) wr[m] = ntld4(wf + (size_t)n[m] * FC_K + k);
  }

  for (int k0 = 0; k0 < FC_KLEN; k0 += 256) {
    int k = kbase + k0 + 4 * l;
    int kp = (k0 + 256 < FC_KLEN) ? (k + 256) : (kbase + 4 * l);
    float4 wrn[4];
#pragma unroll
    for (int m = 0; m < 4; ++m) wrn[m] = ntld4(wf + (size_t)n[m] * FC_K + kp);

#pragma unroll
    for (int bg = 0; bg < 4; ++bg) {
      float4 xv[4];
#pragma unroll
      for (int r = 0; r < 4; ++r)
        xv[r] = *reinterpret_cast<const float4*>(a3t +
                    (size_t)(bg * 4 + r) * FC_K + k);
#pragma unroll
      for (int r = 0; r < 4; ++r) {
        int b = bg * 4 + r;
#pragma unroll
        for (int m = 0; m < 4; ++m) {
          int j = b * 4 + m;
          acc[j] = fmaf(wr[m].x, xv[r].x, acc[j]);
          acc[j] = fmaf(wr[m].y, xv[r].y, acc[j]);
          acc[j] = fmaf(wr[m].z, xv[r].z, acc[j]);
          acc[j] = fmaf(wr[m].w, xv[r].w, acc[j]);
        }
      }
      __builtin_amdgcn_sched_barrier(0);
    }
#pragma unroll
    for (int m = 0; m < 4; ++m) wr[m] = wrn[m];
  }

#pragma unroll
  for (int s = 0; s < 6; ++s) {
    int mask = 1 << s;
    int bit = (l >> s) & 1;
#pragma unroll
    for (int t = 0; t < 32; ++t) {
      if (t < (64 >> (s + 1))) {
        float e = acc[2 * t] + __shfl_xor(acc[2 * t], mask, 64);
        float o = acc[2 * t + 1] + __shfl_xor(acc[2 * t + 1], mask, 64);
        acc[t] = bit ? o : e;
      }
    }
  }

  int b = l >> 2;
  int m = l & 3;
  int nn = n0 + m;
  if (nn < FC_N)
    fcp[((size_t)kc * 16 + b) * FC_N + nn] = acc[0];
}

// ---------- FC stage 2: sum k-chunks + bias ----------
__global__ void k_fc_comb(const float* __restrict__ fcp,
                          const float* __restrict__ bf,
                          float* __restrict__ out, int total) {
  int t = blockIdx.x * blockDim.x + threadIdx.x;
  if (t >= total) return;
  unsigned n = (unsigned)t % (unsigned)FC_N;
  float s = bf[n];
#pragma unroll
  for (int kc = 0; kc < FC_KC; ++kc) s += fcp[(size_t)kc * 16 * FC_N + t];
  out[t] = s;
}

// ---------- launch ----------
static inline int cdiv(int a, int b) { return (a + b - 1) / b; }

extern "C" void kernel_launch(void* const* d_in, const int* in_sizes, int n_in,
                              void* d_out, int out_size, void* d_ws,
                              size_t ws_size, hipStream_t stream) {
  const float* x  = (const float*)d_in[0];  // (16,3,218,178)
  const float* w1 = (const float*)d_in[1];  // (8,3,213,173,36)
  const float* b1 = (const float*)d_in[2];  // (8,213,173)
  const float* w2 = (const float*)d_in[3];  // (16,8,51,41,36)
  const float* b2 = (const float*)d_in[4];  // (16,51,41)
  const float* w3 = (const float*)d_in[5];  // (32,16,16,12,36)
  const float* b3 = (const float*)d_in[6];  // (32,16,12)
  const float* wf = (const float*)d_in[7];  // (10178,6144)
  const float* bf = (const float*)d_in[8];  // (10178,)
  float* out = (float*)d_out;               // (16,10178)

  float* ws = (float*)d_ws;
  float* xt     = ws;                  // region 1,862,592 floats
  float* a1     = ws + 1862592;        // 4,716,672 (free after pool)
  float* a1p    = ws + 6579264;        // 1,166,848 (free after L2 partials)
  float* a2     = ws + 7746112;        //   535,296
  float* a3t    = ws + 8281408;        //    98,304
  unsigned* xh  = (unsigned*)xt;       // fp16 x: 116,412 * 8 u32 (fits)
  float* l2part = a1;                  // 8 * 535,296 = 4,282,368 <= a1
  float* l3part = xt;                  // 16 * 98,304 = 1,572,864 <= xt region
  float* fcp    = a1p;                 // 2 * 162,848 =   325,696 <= a1p

  {  // transpose x -> xh (fp16, batch-paired)
    int total = 3 * 218 * 178;
    k_transpose_h<<<cdiv(total, 256), 256, 0, stream>>>(x, xh, total, total);
  }
  {  // L1: packed-fp16 FMA, 576 tiles x 2 o-groups = 1152 blocks
    k_lc1_h2<<<576 * 2, 256, 0, stream>>>(xh, w1, b1, a1);
  }
  {  // maxpool2 -> 106x86
    int total = 4 * 8 * 106 * 86;
    k_pool<<<cdiv(total, 256), 256, 0, stream>>>(a1, a1p, 213, 173, 106, 86,
                                                 total);
  }
  {  // L2 partials: POS=2091, NT=33, OGN=4, C=8 -> 1056 blocks
    k_lc_lds_part<8, 106, 86, 51, 41, 2, 16>
        <<<33 * 4 * 8, 256, 0, stream>>>(a1p, w2, l2part);
  }
  {  // L2 combine -> a2
    int n4 = 16 * 2091 * 4;
    k_combine<8, false><<<cdiv(n4, 256), 256, 0, stream>>>(l2part, b2, a2, n4);
  }
  {  // L3 partials: POS=192, NT=3, OGN=8, C=16 -> 384 blocks
    k_lc_lds_part<16, 51, 41, 16, 12, 3, 32>
        <<<3 * 8 * 16, 256, 0, stream>>>(a2, w3, l3part);
  }
  {  // L3 combine -> a3t [16][6144]
    int n4 = 32 * 192 * 4;
    k_combine<16, true><<<cdiv(n4, 256), 256, 0, stream>>>(l3part, b3, a3t, n4);
  }
  {  // FC stage 1: (637, 2) -> 5096 waves
    dim3 grid(cdiv(FC_N, 16), FC_KC);
    k_fc<<<grid, 256, 0, stream>>>(a3t, wf, fcp);
  }
  {  // FC stage 2
    int total = 16 * FC_N;
    k_fc_comb<<<cdiv(total, 256), 256, 0, stream>>>(fcp, bf, out, total);
  }
}